// Round 1
// baseline (447.311 us; speedup 1.0000x reference)
//
#include <hip/hip_runtime.h>

#define BB 512
#define CC 3
#define TT 16384
// quads per row = TT/4 = 4096 (shift 12); total quads = BB*4096 = 2,097,152
// grid = 8192 blocks x 256 threads covers it exactly (no bounds check needed)

__global__ __launch_bounds__(256) void ce_trans_kernel(const float* __restrict__ logits,
                                                       const int* __restrict__ labels,
                                                       float* __restrict__ acc) {
    const int q  = blockIdx.x * 256 + threadIdx.x;   // quad index
    const int b  = q >> 12;                          // /4096
    const int tq = q & 4095;
    const int t0 = tq << 2;

    const float* p0 = logits + (size_t)b * (CC * TT) + t0;
    const float4 a4 = *reinterpret_cast<const float4*>(p0);
    const float4 b4 = *reinterpret_cast<const float4*>(p0 + TT);
    const float4 c4 = *reinterpret_cast<const float4*>(p0 + 2 * TT);
    const int4  l4 = *reinterpret_cast<const int4*>(labels + (size_t)b * TT + t0);

    float x0[5] = {a4.x, a4.y, a4.z, a4.w, 0.f};
    float x1[5] = {b4.x, b4.y, b4.z, b4.w, 0.f};
    float x2[5] = {c4.x, c4.y, c4.z, c4.w, 0.f};
    const bool hasNext = (tq != 4095);
    if (hasNext) {          // neighbor's first element: L1 hit, ~0 extra HBM
        x0[4] = p0[4];
        x1[4] = p0[TT + 4];
        x2[4] = p0[2 * TT + 4];
    }
    const int lab[4] = {l4.x, l4.y, l4.z, l4.w};

    float nll = 0.f, ss = 0.f;
    int cnt = 0;
    int am[5];

#pragma unroll
    for (int j = 0; j < 5; ++j) {
        const float v0 = x0[j], v1 = x1[j], v2 = x2[j];
        int idx = 0;
        float mx = v0;
        if (v1 > mx) { mx = v1; idx = 1; }   // strict > == first-occurrence argmax
        if (v2 > mx) { mx = v2; idx = 2; }
        am[j] = idx;
        if (j < 4) {
            const float e   = __expf(v0 - mx) + __expf(v1 - mx) + __expf(v2 - mx);
            const float lse = mx + __logf(e);
            const float xl  = (lab[j] == 0) ? v0 : ((lab[j] == 1) ? v1 : v2);
            nll += lse - xl;
        }
    }

    const int nd = hasNext ? 4 : 3;
#pragma unroll
    for (int j = 0; j < 4; ++j) {
        if (j < nd) {
            const float d0 = x0[j + 1] - x0[j];
            const float d1 = x1[j + 1] - x1[j];
            const float d2 = x2[j + 1] - x2[j];
            ss += d0 * d0 + d1 * d1 + d2 * d2;
            // penalized transitions: (0->2),(2->1),(1->0)  <=>  next == (prev+2)%3
            const int p = am[j], n = am[j + 1];
            cnt += (n == ((p + 2) % 3)) ? 1 : 0;
        }
    }

    // wave64 shuffle reduction
    float fcnt = (float)cnt;
#pragma unroll
    for (int off = 32; off > 0; off >>= 1) {
        nll  += __shfl_down(nll,  off, 64);
        ss   += __shfl_down(ss,   off, 64);
        fcnt += __shfl_down(fcnt, off, 64);
    }

    __shared__ float s_nll[4], s_ss[4], s_cnt[4];
    const int wave = threadIdx.x >> 6;
    const int lane = threadIdx.x & 63;
    if (lane == 0) { s_nll[wave] = nll; s_ss[wave] = ss; s_cnt[wave] = fcnt; }
    __syncthreads();
    if (threadIdx.x == 0) {
        const float tn = s_nll[0] + s_nll[1] + s_nll[2] + s_nll[3];
        const float ts = s_ss[0]  + s_ss[1]  + s_ss[2]  + s_ss[3];
        const float tc = s_cnt[0] + s_cnt[1] + s_cnt[2] + s_cnt[3];
        atomicAdd(acc + 0, tn);
        atomicAdd(acc + 1, ts);
        atomicAdd(acc + 2, tc);
    }
}

__global__ void ce_trans_finalize(const float* __restrict__ acc, float* __restrict__ out) {
    const float ce = acc[0] / 8388608.0f;                 // B*T = 512*16384
    const float sm = 0.01f * (acc[1] / 25164288.0f);      // B*C*(T-1) = 512*3*16383
    const float tp = (acc[2] > 0.5f) ? 0.1f : 0.0f;       // sum(vals)/count == 1 exactly
    out[0] = ce + sm + tp;
}

extern "C" void kernel_launch(void* const* d_in, const int* in_sizes, int n_in,
                              void* d_out, int out_size, void* d_ws, size_t ws_size,
                              hipStream_t stream) {
    const float* logits = (const float*)d_in[0];
    const int*   labels = (const int*)d_in[1];
    float* out = (float*)d_out;
    float* acc = (float*)d_ws;

    hipMemsetAsync(d_ws, 0, 3 * sizeof(float), stream);
    ce_trans_kernel<<<8192, 256, 0, stream>>>(logits, labels, acc);
    ce_trans_finalize<<<1, 1, 0, stream>>>(acc, out);
}

// Round 2
// 173.906 us; speedup vs baseline: 2.5721x; 2.5721x over previous
//
#include <hip/hip_runtime.h>

#define BB 512
#define CC 3
#define TT 16384
// total quads = BB * (TT/4) = 2,097,152
// main grid: 2048 blocks x 256 threads = 524,288 threads; 4 quads/thread (grid-stride)
// partials layout (SoA in d_ws): [0..2047]=nll, [2048..4095]=ss, [4096..6143]=cnt

#define NBLK 2048
#define NTHREADS (NBLK * 256)
#define NQUAD (BB * TT / 4)
#define ITERS (NQUAD / NTHREADS)   // 4

__global__ __launch_bounds__(256) void ce_trans_main(const float* __restrict__ logits,
                                                     const int* __restrict__ labels,
                                                     float* __restrict__ partials) {
    float nll = 0.f, ss = 0.f;
    int cnt = 0;

#pragma unroll
    for (int it = 0; it < ITERS; ++it) {
        const int q  = it * NTHREADS + blockIdx.x * 256 + threadIdx.x;  // quad index
        const int b  = q >> 12;                                          // /4096 quads per row
        const int tq = q & 4095;
        const int t0 = tq << 2;

        const float* p0 = logits + (size_t)b * (CC * TT) + t0;
        const float4 a4 = *reinterpret_cast<const float4*>(p0);
        const float4 b4 = *reinterpret_cast<const float4*>(p0 + TT);
        const float4 c4 = *reinterpret_cast<const float4*>(p0 + 2 * TT);
        const int4   l4 = *reinterpret_cast<const int4*>(labels + (size_t)b * TT + t0);

        float x0[5] = {a4.x, a4.y, a4.z, a4.w, 0.f};
        float x1[5] = {b4.x, b4.y, b4.z, b4.w, 0.f};
        float x2[5] = {c4.x, c4.y, c4.z, c4.w, 0.f};
        const bool hasNext = (tq != 4095);
        if (hasNext) {          // neighbor's first element: L1 hit, ~0 extra HBM
            x0[4] = p0[4];
            x1[4] = p0[TT + 4];
            x2[4] = p0[2 * TT + 4];
        }
        const int lab[4] = {l4.x, l4.y, l4.z, l4.w};

        int am[5];
#pragma unroll
        for (int j = 0; j < 5; ++j) {
            const float v0 = x0[j], v1 = x1[j], v2 = x2[j];
            int idx = 0;
            float mx = v0;
            if (v1 > mx) { mx = v1; idx = 1; }   // strict > == first-occurrence argmax
            if (v2 > mx) { mx = v2; idx = 2; }
            am[j] = idx;
            if (j < 4) {
                const float e   = __expf(v0 - mx) + __expf(v1 - mx) + __expf(v2 - mx);
                const float lse = mx + __logf(e);
                const float xl  = (lab[j] == 0) ? v0 : ((lab[j] == 1) ? v1 : v2);
                nll += lse - xl;
            }
        }

        const int nd = hasNext ? 4 : 3;
#pragma unroll
        for (int j = 0; j < 4; ++j) {
            if (j < nd) {
                const float d0 = x0[j + 1] - x0[j];
                const float d1 = x1[j + 1] - x1[j];
                const float d2 = x2[j + 1] - x2[j];
                ss += d0 * d0 + d1 * d1 + d2 * d2;
                // penalized transitions: (0->2),(2->1),(1->0)  <=>  next == (prev+2)%3
                cnt += (am[j + 1] == ((am[j] + 2) % 3)) ? 1 : 0;
            }
        }
    }

    // wave64 shuffle reduction
    float fcnt = (float)cnt;
#pragma unroll
    for (int off = 32; off > 0; off >>= 1) {
        nll  += __shfl_down(nll,  off, 64);
        ss   += __shfl_down(ss,   off, 64);
        fcnt += __shfl_down(fcnt, off, 64);
    }

    __shared__ float s_nll[4], s_ss[4], s_cnt[4];
    const int wave = threadIdx.x >> 6;
    const int lane = threadIdx.x & 63;
    if (lane == 0) { s_nll[wave] = nll; s_ss[wave] = ss; s_cnt[wave] = fcnt; }
    __syncthreads();
    if (threadIdx.x == 0) {
        partials[blockIdx.x]            = s_nll[0] + s_nll[1] + s_nll[2] + s_nll[3];
        partials[NBLK + blockIdx.x]     = s_ss[0]  + s_ss[1]  + s_ss[2]  + s_ss[3];
        partials[2 * NBLK + blockIdx.x] = s_cnt[0] + s_cnt[1] + s_cnt[2] + s_cnt[3];
    }
}

__global__ __launch_bounds__(256) void ce_trans_final(const float* __restrict__ partials,
                                                      float* __restrict__ out) {
    float sn = 0.f, st = 0.f, sc = 0.f;
    for (int i = threadIdx.x; i < NBLK; i += 256) {
        sn += partials[i];
        st += partials[NBLK + i];
        sc += partials[2 * NBLK + i];
    }
#pragma unroll
    for (int off = 32; off > 0; off >>= 1) {
        sn += __shfl_down(sn, off, 64);
        st += __shfl_down(st, off, 64);
        sc += __shfl_down(sc, off, 64);
    }
    __shared__ float s_n[4], s_s[4], s_c[4];
    const int wave = threadIdx.x >> 6;
    const int lane = threadIdx.x & 63;
    if (lane == 0) { s_n[wave] = sn; s_s[wave] = st; s_c[wave] = sc; }
    __syncthreads();
    if (threadIdx.x == 0) {
        const float tn = s_n[0] + s_n[1] + s_n[2] + s_n[3];
        const float ts = s_s[0] + s_s[1] + s_s[2] + s_s[3];
        const float tc = s_c[0] + s_c[1] + s_c[2] + s_c[3];
        const float ce = tn / 8388608.0f;              // B*T
        const float sm = 0.01f * (ts / 25164288.0f);   // B*C*(T-1)
        const float tp = (tc > 0.5f) ? 0.1f : 0.0f;    // sum(vals)/count == 1 exactly
        out[0] = ce + sm + tp;
    }
}

extern "C" void kernel_launch(void* const* d_in, const int* in_sizes, int n_in,
                              void* d_out, int out_size, void* d_ws, size_t ws_size,
                              hipStream_t stream) {
    const float* logits = (const float*)d_in[0];
    const int*   labels = (const int*)d_in[1];
    float* out      = (float*)d_out;
    float* partials = (float*)d_ws;   // 3 * 2048 floats = 24 KB

    ce_trans_main<<<NBLK, 256, 0, stream>>>(logits, labels, partials);
    ce_trans_final<<<1, 256, 0, stream>>>(partials, out);
}

// Round 3
// 167.791 us; speedup vs baseline: 2.6659x; 1.0364x over previous
//
#include <hip/hip_runtime.h>

typedef float v4f __attribute__((ext_vector_type(4)));
typedef int   v4i __attribute__((ext_vector_type(4)));

#define BB 512
#define CC 3
#define TT 16384
#define NBLK 2048
#define NTHREADS (NBLK * 256)          // 524288 threads
#define NQUAD (BB * TT / 4)            // 2,097,152 quads
#define ITERS (NQUAD / NTHREADS)       // 4 quads per thread
// partials (SoA in d_ws): [0..2047]=nll, [2048..4095]=ss, [4096..6143]=cnt
// penalized transitions (prev,next) in {(0,2),(2,1),(1,0)} -> 3*p+n in {2,7,3} -> mask 0x8C

__global__ __launch_bounds__(256) void ce_trans_main(const float* __restrict__ logits,
                                                     const int* __restrict__ labels,
                                                     float* __restrict__ partials) {
    const int tid0 = blockIdx.x * 256 + threadIdx.x;
    const int lane = threadIdx.x & 63;

    float nll = 0.f, ss = 0.f;
    int cnt = 0;

    // 2-deep software pipeline state
    v4f A[2], Bv[2], Cv[2];
    v4i Lv[2];
    int TQ[2];
    const float* P0[2];

    auto issue = [&](int it, int slot) {
        const int q  = it * NTHREADS + tid0;
        const int b  = q >> 12;          // 4096 quads per (b) row
        const int tq = q & 4095;
        const float* p0 = logits + (size_t)b * (CC * TT) + (tq << 2);
        A[slot]  = __builtin_nontemporal_load((const v4f*)p0);
        Bv[slot] = __builtin_nontemporal_load((const v4f*)(p0 + TT));
        Cv[slot] = __builtin_nontemporal_load((const v4f*)(p0 + 2 * TT));
        Lv[slot] = __builtin_nontemporal_load((const v4i*)(labels + (size_t)b * TT + (tq << 2)));
        TQ[slot] = tq;
        P0[slot] = p0;
    };

    auto compute = [&](int slot) {
        const v4f a = A[slot], bq = Bv[slot], c = Cv[slot];
        const v4i l = Lv[slot];
        const float x0[4] = {a.x,  a.y,  a.z,  a.w};
        const float x1[4] = {bq.x, bq.y, bq.z, bq.w};
        const float x2[4] = {c.x,  c.y,  c.z,  c.w};
        const int  lab[4] = {l.x,  l.y,  l.z,  l.w};
        int am[4];

#pragma unroll
        for (int j = 0; j < 4; ++j) {
            const float v0 = x0[j], v1 = x1[j], v2 = x2[j];
            int idx = 0;
            float mx = v0;
            if (v1 > mx) { mx = v1; idx = 1; }   // strict > == first-occurrence argmax
            if (v2 > mx) { mx = v2; idx = 2; }
            am[j] = idx;
            const float e  = __expf(v0 - mx) + __expf(v1 - mx) + __expf(v2 - mx);
            const float xl = (lab[j] == 0) ? v0 : ((lab[j] == 1) ? v1 : v2);
            nll += mx + __logf(e) - xl;
        }

#pragma unroll
        for (int j = 0; j < 3; ++j) {
            const float d0 = x0[j + 1] - x0[j];
            const float d1 = x1[j + 1] - x1[j];
            const float d2 = x2[j + 1] - x2[j];
            ss += d0 * d0 + d1 * d1 + d2 * d2;
            cnt += (0x8C >> (3 * am[j] + am[j + 1])) & 1;
        }

        // boundary element t0+4 = neighbor lane's first element (waves never straddle rows:
        // one row = 4096 quads = 64 full waves)
        float xn0 = __shfl_down(x0[0], 1, 64);
        float xn1 = __shfl_down(x1[0], 1, 64);
        float xn2 = __shfl_down(x2[0], 1, 64);
        int   amn = __shfl_down(am[0], 1, 64);
        bool valid = true;
        if (lane == 63) {
            if (TQ[slot] == 4095) {
                valid = false;                    // row end: no t+1 neighbor
            } else {
                const float* p0 = P0[slot];
                xn0 = p0[4]; xn1 = p0[TT + 4]; xn2 = p0[2 * TT + 4];
                int idx = 0;
                float mx = xn0;
                if (xn1 > mx) { mx = xn1; idx = 1; }
                if (xn2 > mx) { mx = xn2; idx = 2; }
                amn = idx;
            }
        }
        if (valid) {
            const float d0 = xn0 - x0[3];
            const float d1 = xn1 - x1[3];
            const float d2 = xn2 - x2[3];
            ss += d0 * d0 + d1 * d1 + d2 * d2;
            cnt += (0x8C >> (3 * am[3] + amn)) & 1;
        }
    };

    issue(0, 0);
#pragma unroll
    for (int it = 0; it < ITERS; ++it) {
        if (it + 1 < ITERS) issue(it + 1, (it + 1) & 1);
        compute(it & 1);
    }

    // wave64 shuffle reduction
    float fcnt = (float)cnt;
#pragma unroll
    for (int off = 32; off > 0; off >>= 1) {
        nll  += __shfl_down(nll,  off, 64);
        ss   += __shfl_down(ss,   off, 64);
        fcnt += __shfl_down(fcnt, off, 64);
    }

    __shared__ float s_nll[4], s_ss[4], s_cnt[4];
    const int wave = threadIdx.x >> 6;
    if ((threadIdx.x & 63) == 0) { s_nll[wave] = nll; s_ss[wave] = ss; s_cnt[wave] = fcnt; }
    __syncthreads();
    if (threadIdx.x == 0) {
        partials[blockIdx.x]            = s_nll[0] + s_nll[1] + s_nll[2] + s_nll[3];
        partials[NBLK + blockIdx.x]     = s_ss[0]  + s_ss[1]  + s_ss[2]  + s_ss[3];
        partials[2 * NBLK + blockIdx.x] = s_cnt[0] + s_cnt[1] + s_cnt[2] + s_cnt[3];
    }
}

__global__ __launch_bounds__(256) void ce_trans_final(const float* __restrict__ partials,
                                                      float* __restrict__ out) {
    float sn = 0.f, st = 0.f, sc = 0.f;
    // each stream: 2048 floats = 512 float4; 256 threads x 2 float4
#pragma unroll
    for (int k = 0; k < 2; ++k) {
        const int i = k * 256 + threadIdx.x;
        const v4f n4 = *((const v4f*)partials + i);
        const v4f s4 = *((const v4f*)partials + 512 + i);
        const v4f c4 = *((const v4f*)partials + 1024 + i);
        sn += n4.x + n4.y + n4.z + n4.w;
        st += s4.x + s4.y + s4.z + s4.w;
        sc += c4.x + c4.y + c4.z + c4.w;
    }
#pragma unroll
    for (int off = 32; off > 0; off >>= 1) {
        sn += __shfl_down(sn, off, 64);
        st += __shfl_down(st, off, 64);
        sc += __shfl_down(sc, off, 64);
    }
    __shared__ float s_n[4], s_s[4], s_c[4];
    const int wave = threadIdx.x >> 6;
    if ((threadIdx.x & 63) == 0) { s_n[wave] = sn; s_s[wave] = st; s_c[wave] = sc; }
    __syncthreads();
    if (threadIdx.x == 0) {
        const float tn = s_n[0] + s_n[1] + s_n[2] + s_n[3];
        const float ts = s_s[0] + s_s[1] + s_s[2] + s_s[3];
        const float tc = s_c[0] + s_c[1] + s_c[2] + s_c[3];
        const float ce = tn / 8388608.0f;              // B*T
        const float sm = 0.01f * (ts / 25164288.0f);   // B*C*(T-1)
        const float tp = (tc > 0.5f) ? 0.1f : 0.0f;    // all table values are 1 => sum/count == 1
        out[0] = ce + sm + tp;
    }
}

extern "C" void kernel_launch(void* const* d_in, const int* in_sizes, int n_in,
                              void* d_out, int out_size, void* d_ws, size_t ws_size,
                              hipStream_t stream) {
    const float* logits = (const float*)d_in[0];
    const int*   labels = (const int*)d_in[1];
    float* out      = (float*)d_out;
    float* partials = (float*)d_ws;   // 3 * 2048 floats = 24 KB

    ce_trans_main<<<NBLK, 256, 0, stream>>>(logits, labels, partials);
    ce_trans_final<<<1, 256, 0, stream>>>(partials, out);
}